// Round 6
// baseline (8454.417 us; speedup 1.0000x reference)
//
#include <hip/hip_runtime.h>
#include <math.h>

// B=512, D_MODEL=1024, D_INNER=2048, DT_RANK=64, D_STATE=64, NBC=192,
// C_OUT=64, PRED_LEN=96.
// R6: 32 groups (16 batch rows) x 16 slices (128 cols) = 512 blocks x 512
// threads, 2 blocks/CU (launch_bounds(512,4) -> <=128 VGPR). blockIdx =
// g*16+i: co-resident CU partners are different groups (barrier overlap);
// slice i's weights pinned to XCD i%8 (L2-resident, ~437KB/XCD).
// Cross-block: plain agent-scope stores; per-row reducer (block i = row i);
// 4 group barriers/step via atomic counters.

#define AGENT __HIP_MEMORY_SCOPE_AGENT
typedef unsigned long long ull;

__device__ __forceinline__ float sigf(float v){
  return __builtin_amdgcn_rcpf(1.f + __expf(-v));
}

// ---------------- setup kernels ----------------

__global__ __launch_bounds__(256) void k_ctx(
    const float* __restrict__ ctxin, const float* __restrict__ w_in,
    const float* __restrict__ b_in, float* __restrict__ ctx_xz){
  int tid = threadIdx.x;
  int j = blockIdx.x*256 + tid;
  int b0 = blockIdx.y*16;
  const float* cp = ctxin + (size_t)b0*1024;
  float acc[16];
#pragma unroll
  for (int r=0;r<16;r++) acc[r]=0.f;
  for (int k=0;k<1024;k+=4){
    float w0 = w_in[(size_t)(k+0)*4096 + j];
    float w1 = w_in[(size_t)(k+1)*4096 + j];
    float w2 = w_in[(size_t)(k+2)*4096 + j];
    float w3 = w_in[(size_t)(k+3)*4096 + j];
#pragma unroll
    for (int r=0;r<16;r++){
      acc[r] += cp[r*1024+k]*w0 + cp[r*1024+k+1]*w1
              + cp[r*1024+k+2]*w2 + cp[r*1024+k+3]*w3;
    }
  }
  float bj = b_in[j];
#pragma unroll
  for (int r=0;r<16;r++) ctx_xz[(size_t)(b0+r)*4096 + j] = acc[r] + bj;
}

// W_op[c][o] = sum_k w_out[c][k]*w_proj[k][o]; b_op = b_out@w_proj + b_proj
__global__ __launch_bounds__(256) void k_wop(
    const float* __restrict__ w_out, const float* __restrict__ w_proj,
    const float* __restrict__ b_out, const float* __restrict__ b_proj,
    float* __restrict__ W_op, float* __restrict__ b_op){
  int g = blockIdx.x, tid = threadIdx.x;
  if (g == 512){
    if (tid < 64){
      float s = b_proj[tid];
      for (int k=0;k<1024;k++) s += b_out[k]*w_proj[k*64+tid];
      b_op[tid] = s;
    }
    return;
  }
  int idx = g*256 + tid;
  int c = idx>>6, o = idx&63;
  float s = 0.f;
  const float* wr = w_out + (size_t)c*1024;
  for (int k=0;k<1024;k++) s += wr[k]*w_proj[k*64+o];
  W_op[idx] = s;
}

__global__ __launch_bounds__(256) void k_cvec(
    const float* __restrict__ b_op, const float* __restrict__ w_in2,
    float* __restrict__ cvec){
  int j = blockIdx.x*256 + threadIdx.x;
  float s = 0.f;
  for (int o=0;o<64;o++) s += b_op[o]*w_in2[(size_t)o*4096 + j];
  cvec[j] = s;
}

__global__ void k_zero(int* __restrict__ p, int n){
  int i = blockIdx.x*256 + threadIdx.x;
  if (i < n) p[i] = 0;
}

// ---------------- persistent step kernel ----------------

__device__ __forceinline__ void gbar(int* flag, int target){
  __syncthreads();   // drains vmcnt: this block's agent stores are out
  if (threadIdx.x == 0){
    __hip_atomic_fetch_add(flag, 1, __ATOMIC_RELEASE, AGENT);
    while (__hip_atomic_load(flag, __ATOMIC_RELAXED, AGENT) < target)
      __builtin_amdgcn_s_sleep(1);
  }
  __syncthreads();
}

__global__ __launch_bounds__(512,4) void k_steps(
    const float* __restrict__ ctx_xz, const float* __restrict__ cvec,
    const float* __restrict__ w_in2,  const float* __restrict__ conv_w,
    const float* __restrict__ conv_b, const float* __restrict__ w_x,
    const float* __restrict__ w_dt,   const float* __restrict__ b_dt,
    const float* __restrict__ D_skip, const float* __restrict__ W_op,
    const float* __restrict__ b_op,   const float* __restrict__ initial,
    float* __restrict__ pXd, float* __restrict__ xdR,
    float* __restrict__ pPd, float* __restrict__ predR,
    float* __restrict__ bcG, int* __restrict__ flags,
    float* __restrict__ dout)
{
  const int tid  = threadIdx.x;
  const int g    = blockIdx.x >> 4;   // group: 16 batch rows
  const int i    = blockIdx.x & 15;   // slice: 128 cols; also: reducer for row i
  const int r0   = g*16;
  const int c    = tid & 127;
  const int rq   = tid >> 7;          // 0..3 (rows rq*4..+3)
  const int lane = tid & 63;
  const int rp   = tid >> 6;          // 0..7 (row pairs / partial pairs)
  const int jx   = i*128 + c;
  const int jz   = 2048 + jx;

  __shared__ float pdtL[64][20];   // predL (phase A) / dtL (phase C), [o][r]
  __shared__ float xyL[128][20];   // x tile then y tile, [k][r]
  __shared__ float xdRed[192];
  __shared__ float predRed[64];
  __shared__ float bcL[16];

  // step-invariant per-thread constants
  const float cw   = conv_w[jx*4+3];
  const float cbv  = conv_b[jx];
  const float cvx  = cvec[jx];
  const float cvz  = cvec[jz];
  const float bdtv = b_dt[jx];
  const float dskv = D_skip[jx];
  const float bopv = b_op[lane];
  float ctxx[4], ctxz[4];
#pragma unroll
  for (int r=0;r<4;r++){
    ctxx[r] = ctx_xz[(size_t)(r0+rq*4+r)*4096 + jx];
    ctxz[r] = ctx_xz[(size_t)(r0+rq*4+r)*4096 + jz];
  }

  float* pXd_blk = pXd + (size_t)blockIdx.x*3072;
  float* pPd_blk = pPd + (size_t)blockIdx.x*1024;
  float* xdR_g   = xdR + (size_t)g*3072;
  float* predR_g = predR + (size_t)g*1024;
  int*   flag    = flags + g*32;

  for (int t=0; t<96; t++){
    // ---- phase A: stage predL [o][r] ----
    {
      float v0, v1;
      if (t == 0){
        v0 = initial[(size_t)(r0+rp*2  )*64 + lane];
        v1 = initial[(size_t)(r0+rp*2+1)*64 + lane];
      } else {
        v0 = __hip_atomic_load(&predR_g[(rp*2  )*64 + lane], __ATOMIC_RELAXED, AGENT);
        v1 = __hip_atomic_load(&predR_g[(rp*2+1)*64 + lane], __ATOMIC_RELAXED, AGENT);
      }
      pdtL[lane][rp*2]   = v0;
      pdtL[lane][rp*2+1] = v1;
    }
    __syncthreads();

    // ---- GEMM1: x,z halves (K=64 over pred) ----
    const float tf = (t > 0) ? 1.f : 0.f;
    float ax[4], az[4];
#pragma unroll
    for (int r=0;r<4;r++){
      ax[r] = fmaf(tf, cvx, ctxx[r]);
      az[r] = fmaf(tf, cvz, ctxz[r]);
    }
    {
      const float* w2 = w_in2 + jx;
#pragma unroll 8
      for (int o=0;o<64;o++){
        float wx = w2[(size_t)o*4096];
        float wz = w2[(size_t)o*4096 + 2048];
        float4 p = *(const float4*)&pdtL[o][rq*4];
        ax[0]+=p.x*wx; ax[1]+=p.y*wx; ax[2]+=p.z*wx; ax[3]+=p.w*wx;
        az[0]+=p.x*wz; az[1]+=p.y*wz; az[2]+=p.z*wz; az[3]+=p.w*wz;
      }
    }
    float xv[4], zs[4];
#pragma unroll
    for (int r=0;r<4;r++){
      float v = ax[r]*cw + cbv;
      xv[r] = v*sigf(v);
      zs[r] = az[r]*sigf(az[r]);
    }
    *(float4*)&xyL[c][rq*4] = make_float4(xv[0],xv[1],xv[2],xv[3]);
    __syncthreads();

    // ---- xdbc partials over this slice's K=128 ----
    if (tid < 384){
      const int n  = (tid < 192) ? tid : tid - 192;
      const int rb = (tid < 192) ? 0 : 8;
      const float* wx = w_x + (size_t)(i*128)*192 + n;
      float f[8] = {0,0,0,0,0,0,0,0};
#pragma unroll 4
      for (int k=0;k<128;k++){
        float w = wx[(size_t)k*192];
        float4 a = *(const float4*)&xyL[k][rb];
        float4 b = *(const float4*)&xyL[k][rb+4];
        f[0]+=a.x*w; f[1]+=a.y*w; f[2]+=a.z*w; f[3]+=a.w*w;
        f[4]+=b.x*w; f[5]+=b.y*w; f[6]+=b.z*w; f[7]+=b.w*w;
      }
#pragma unroll
      for (int j=0;j<8;j++)
        __hip_atomic_store(&pXd_blk[(rb+j)*192 + n], f[j], __ATOMIC_RELAXED, AGENT);
    } else {
      int q = tid - 384;           // 0..127: zero LDS reduction targets
      xdRed[q] = 0.f;
      if (q < 64){ xdRed[128+q] = 0.f; predRed[q] = 0.f; }
    }
    gbar(flag, 16*(4*t+1));

    // ---- reduce xdbc: block i owns row i (192 outputs) ----
    if (tid < 384){
      const int t2 = (tid < 192) ? tid : tid - 192;
      const int s0 = (tid < 192) ? 0 : 8;
      float s = 0.f;
#pragma unroll
      for (int u=0;u<8;u++)
        s += __hip_atomic_load(&pXd[(size_t)(g*16+s0+u)*3072 + i*192 + t2],
                               __ATOMIC_RELAXED, AGENT);
      atomicAdd(&xdRed[t2], s);
    }
    __syncthreads();
    if (tid < 192)
      __hip_atomic_store(&xdR_g[i*192 + tid], xdRed[tid], __ATOMIC_RELAXED, AGENT);
    if (rp == 0){   // bc for row i, computed once here
      float p = xdRed[64+lane]*xdRed[128+lane];
#pragma unroll
      for (int sh=1; sh<64; sh<<=1) p += __shfl_xor(p, sh, 64);
      if (lane == 0)
        __hip_atomic_store(&bcG[g*16 + i], p, __ATOMIC_RELAXED, AGENT);
    }
    gbar(flag, 16*(4*t+2));

    // ---- phase C: stage dtL [o][r] + bcL ----
    {
      float d0 = __hip_atomic_load(&xdR_g[(rp*2  )*192 + lane], __ATOMIC_RELAXED, AGENT);
      float d1 = __hip_atomic_load(&xdR_g[(rp*2+1)*192 + lane], __ATOMIC_RELAXED, AGENT);
      pdtL[lane][rp*2]   = d0;
      pdtL[lane][rp*2+1] = d1;
      if (tid < 16)
        bcL[tid] = __hip_atomic_load(&bcG[g*16 + tid], __ATOMIC_RELAXED, AGENT);
    }
    __syncthreads();

    // ---- dt GEMM (K=64) + y ----
    float da[4] = {0,0,0,0};
    {
      const float* wd = w_dt + jx;
#pragma unroll 8
      for (int o=0;o<64;o++){
        float w = wd[(size_t)o*2048];
        float4 d = *(const float4*)&pdtL[o][rq*4];
        da[0]+=d.x*w; da[1]+=d.y*w; da[2]+=d.z*w; da[3]+=d.w*w;
      }
    }
    float yv[4];
#pragma unroll
    for (int r=0;r<4;r++){
      float v = da[r] + bdtv;
      float dt = (v > 15.f) ? v : __logf(1.f + __expf(v));
      yv[r] = (dt*bcL[rq*4+r] + dskv) * xv[r] * zs[r];
    }
    *(float4*)&xyL[c][rq*4] = make_float4(yv[0],yv[1],yv[2],yv[3]);
    __syncthreads();

    // ---- pred partials over this slice's K=128 ----
    {
      const float* wp = W_op + (size_t)(i*128)*64 + lane;
      float p0 = 0.f, p1 = 0.f;
#pragma unroll 4
      for (int k=0;k<128;k++){
        float w = wp[(size_t)k*64];
        p0 += xyL[k][rp*2]*w;
        p1 += xyL[k][rp*2+1]*w;
      }
      __hip_atomic_store(&pPd_blk[(rp*2  )*64 + lane], p0, __ATOMIC_RELAXED, AGENT);
      __hip_atomic_store(&pPd_blk[(rp*2+1)*64 + lane], p1, __ATOMIC_RELAXED, AGENT);
    }
    gbar(flag, 16*(4*t+3));

    // ---- reduce pred: block i owns row i (64 outputs) ----
    {
      float s = __hip_atomic_load(&pPd[(size_t)(g*16+rp*2  )*1024 + i*64 + lane],
                                  __ATOMIC_RELAXED, AGENT)
              + __hip_atomic_load(&pPd[(size_t)(g*16+rp*2+1)*1024 + i*64 + lane],
                                  __ATOMIC_RELAXED, AGENT);
      atomicAdd(&predRed[lane], s);
    }
    __syncthreads();
    if (tid < 64){
      float v = predRed[tid];
      __hip_atomic_store(&predR_g[i*64 + tid], v, __ATOMIC_RELAXED, AGENT);
      dout[((size_t)(r0+i)*96 + t)*64 + tid] = v + bopv;
    }
    gbar(flag, 16*(4*t+4));
  }
}

// ---------------- launch ----------------

extern "C" void kernel_launch(void* const* d_in, const int* in_sizes, int n_in,
                              void* d_out, int out_size, void* d_ws, size_t ws_size,
                              hipStream_t stream)
{
  const float* context = (const float*)d_in[0];
  const float* initial = (const float*)d_in[1];
  const float* w_in    = (const float*)d_in[2];
  const float* b_in    = (const float*)d_in[3];
  const float* conv_w  = (const float*)d_in[4];
  const float* conv_b  = (const float*)d_in[5];
  const float* w_x     = (const float*)d_in[6];
  const float* w_dt    = (const float*)d_in[7];
  const float* b_dt    = (const float*)d_in[8];
  // d_in[9] = A_log (unused: L=1, h0=0)
  const float* D_skip  = (const float*)d_in[10];
  const float* w_out   = (const float*)d_in[11];
  const float* b_out   = (const float*)d_in[12];
  const float* w_proj  = (const float*)d_in[13];
  const float* b_proj  = (const float*)d_in[14];

  float* ws = (float*)d_ws;
  float* ctx_xz = ws;                     // 2,097,152
  float* cvec   = ctx_xz + 2097152;       // 4,096
  float* W_op   = cvec + 4096;            // 131,072
  float* b_op   = W_op + 131072;          // 128
  float* pXd    = b_op + 128;             // 512*3072 = 1,572,864
  float* xdR    = pXd + 1572864;          // 32*3072  = 98,304
  float* pPd    = xdR + 98304;            // 512*1024 = 524,288
  float* predR  = pPd + 524288;           // 32*1024  = 32,768
  float* bcG    = predR + 32768;          // 512
  int*   flags  = (int*)(bcG + 512);      // 1,024 ints
  float* dout   = (float*)d_out;

  const float* w_in2 = w_in + (size_t)1024*4096;

  k_wop <<<dim3(513),   256, 0, stream>>>(w_out, w_proj, b_out, b_proj, W_op, b_op);
  k_cvec<<<dim3(16),    256, 0, stream>>>(b_op, w_in2, cvec);
  k_ctx <<<dim3(16,32), 256, 0, stream>>>(context, w_in, b_in, ctx_xz);
  k_zero<<<dim3(4),     256, 0, stream>>>(flags, 1024);

  k_steps<<<dim3(512), 512, 0, stream>>>(ctx_xz, cvec, w_in2, conv_w, conv_b,
                                         w_x, w_dt, b_dt, D_skip, W_op, b_op,
                                         initial, pXd, xdR, pPd, predR,
                                         bcG, flags, dout);
}

// Round 7
// 3633.733 us; speedup vs baseline: 2.3266x; 2.3266x over previous
//
#include <hip/hip_runtime.h>
#include <math.h>

// B=512, D_MODEL=1024, D_INNER=2048, DT_RANK=64, D_STATE=64, NBC=192,
// C_OUT=64, PRED_LEN=96.
// R7: ZERO-SYNC row-stationary design. 256 blocks x 1024 threads, 1 block/CU,
// 2 batch rows per block, owned end-to-end for all 96 steps. No inter-block
// communication at all (no atomics, no flags): the only sync is intra-block
// __syncthreads. Each block streams the full weight set (3.5MB fp32) from its
// XCD L2 every step -> predicted ~24us/step L2-BW bound.
// All hot-loop LDS reads are wave-uniform broadcasts or contiguous b128.

__device__ __forceinline__ float sigf(float v){
  return __builtin_amdgcn_rcpf(1.f + __expf(-v));
}

// ---------------- setup kernels ----------------

__global__ __launch_bounds__(256) void k_ctx(
    const float* __restrict__ ctxin, const float* __restrict__ w_in,
    const float* __restrict__ b_in, float* __restrict__ ctx_xz){
  int tid = threadIdx.x;
  int j = blockIdx.x*256 + tid;
  int b0 = blockIdx.y*16;
  const float* cp = ctxin + (size_t)b0*1024;
  float acc[16];
#pragma unroll
  for (int r=0;r<16;r++) acc[r]=0.f;
  for (int k=0;k<1024;k+=4){
    float w0 = w_in[(size_t)(k+0)*4096 + j];
    float w1 = w_in[(size_t)(k+1)*4096 + j];
    float w2 = w_in[(size_t)(k+2)*4096 + j];
    float w3 = w_in[(size_t)(k+3)*4096 + j];
#pragma unroll
    for (int r=0;r<16;r++){
      acc[r] += cp[r*1024+k]*w0 + cp[r*1024+k+1]*w1
              + cp[r*1024+k+2]*w2 + cp[r*1024+k+3]*w3;
    }
  }
  float bj = b_in[j];
#pragma unroll
  for (int r=0;r<16;r++) ctx_xz[(size_t)(b0+r)*4096 + j] = acc[r] + bj;
}

// W_op[c][o] = sum_k w_out[c][k]*w_proj[k][o]; b_op = b_out@w_proj + b_proj
__global__ __launch_bounds__(256) void k_wop(
    const float* __restrict__ w_out, const float* __restrict__ w_proj,
    const float* __restrict__ b_out, const float* __restrict__ b_proj,
    float* __restrict__ W_op, float* __restrict__ b_op){
  int g = blockIdx.x, tid = threadIdx.x;
  if (g == 512){
    if (tid < 64){
      float s = b_proj[tid];
      for (int k=0;k<1024;k++) s += b_out[k]*w_proj[k*64+tid];
      b_op[tid] = s;
    }
    return;
  }
  int idx = g*256 + tid;
  int c = idx>>6, o = idx&63;
  float s = 0.f;
  const float* wr = w_out + (size_t)c*1024;
  for (int k=0;k<1024;k++) s += wr[k]*w_proj[k*64+o];
  W_op[idx] = s;
}

__global__ __launch_bounds__(256) void k_cvec(
    const float* __restrict__ b_op, const float* __restrict__ w_in2,
    float* __restrict__ cvec){
  int j = blockIdx.x*256 + threadIdx.x;
  float s = 0.f;
  for (int o=0;o<64;o++) s += b_op[o]*w_in2[(size_t)o*4096 + j];
  cvec[j] = s;
}

// ---------------- persistent step kernel (no inter-block sync) ----------------

__global__ __launch_bounds__(1024,4) void k_steps(
    const float* __restrict__ ctx_xz, const float* __restrict__ cvec,
    const float* __restrict__ w_in2,  const float* __restrict__ conv_w,
    const float* __restrict__ conv_b, const float* __restrict__ w_x,
    const float* __restrict__ w_dt,   const float* __restrict__ b_dt,
    const float* __restrict__ D_skip, const float* __restrict__ W_op,
    const float* __restrict__ b_op,   const float* __restrict__ initial,
    float* __restrict__ dout)
{
  const int tid = threadIdx.x;
  const int r0  = blockIdx.x * 2;     // this block's 2 batch rows

  __shared__ float predL[130];        // pred [o*2+r] (raw, no b_op)
  __shared__ float xbuf[2][2048];     // x tile, later y tile (in-place)
  __shared__ float zbuf[2][2048];     // silu(z) tile
  __shared__ float xdbcF[384];        // reduced xdbc [n*2+r]
  __shared__ float bcL[2];
  __shared__ float pxd[4][384];       // xdbc k-slice partials
  __shared__ float ppd[16][130];      // pred k-slice partials (pad 130)

  // ---- step-invariant per-thread preloads ----
  // Phase-1 mapping: cols cb..cb+3 of xz (0..4095)
  const int cb = tid*4;
  const bool isx = (cb < 2048);
  float4 cw4, cb4;
  if (isx){
    cw4 = make_float4(conv_w[(cb+0)*4+3], conv_w[(cb+1)*4+3],
                      conv_w[(cb+2)*4+3], conv_w[(cb+3)*4+3]);
    cb4 = *(const float4*)&conv_b[cb];
  }
  const float4 cv4   = *(const float4*)&cvec[cb];
  const float4 ctxr0 = *(const float4*)&ctx_xz[(size_t)(r0+0)*4096 + cb];
  const float4 ctxr1 = *(const float4*)&ctx_xz[(size_t)(r0+1)*4096 + cb];
  // Phase-3 mapping: cols c2, c2+1 of d_inner (0..2047)
  const int c2 = tid*2;
  const float2 bdt2 = *(const float2*)&b_dt[c2];
  const float2 dsk2 = *(const float2*)&D_skip[c2];
  // Phase-2 mapping: n (0..191) x k-slice (512 each), 768 threads active
  const int n2  = tid % 192;
  const int ks2 = tid / 192;
  // Phase-4 mapping: o (0..63) x k-slice (128 each), all 1024 threads
  const int o4  = tid & 63;
  const int kb4 = (tid >> 6) * 128;
  // Reducer mapping (tid<128): o = tid>>1, r = tid&1
  const float bopv = b_op[(tid>>1) & 63];

  // init pred = initial
  if (tid < 128)
    predL[tid] = initial[(size_t)(r0 + (tid&1))*64 + (tid>>1)];
  __syncthreads();

  for (int t=0; t<96; t++){
    // ---- P1: xz = ctx (+cvec) + pred @ w_in2 ; x=silu(conv), zs=silu ----
    const float tf = (t > 0) ? 1.f : 0.f;
    float a0[4], a1[4];
#pragma unroll
    for (int i=0;i<4;i++){
      float c = (&cv4.x)[i];
      a0[i] = (&ctxr0.x)[i] + tf*c;
      a1[i] = (&ctxr1.x)[i] + tf*c;
    }
    {
      const float* w2 = w_in2 + cb;
#pragma unroll 8
      for (int o=0;o<64;o++){
        float4 w  = *(const float4*)&w2[(size_t)o*4096];
        float2 p  = *(const float2*)&predL[o*2];
        a0[0]+=w.x*p.x; a0[1]+=w.y*p.x; a0[2]+=w.z*p.x; a0[3]+=w.w*p.x;
        a1[0]+=w.x*p.y; a1[1]+=w.y*p.y; a1[2]+=w.z*p.y; a1[3]+=w.w*p.y;
      }
    }
    if (isx){
      float4 x0, x1;
#pragma unroll
      for (int i=0;i<4;i++){
        float v0 = a0[i]*(&cw4.x)[i] + (&cb4.x)[i];
        float v1 = a1[i]*(&cw4.x)[i] + (&cb4.x)[i];
        (&x0.x)[i] = v0*sigf(v0);
        (&x1.x)[i] = v1*sigf(v1);
      }
      *(float4*)&xbuf[0][cb] = x0;
      *(float4*)&xbuf[1][cb] = x1;
    } else {
      float4 z0, z1;
#pragma unroll
      for (int i=0;i<4;i++){
        (&z0.x)[i] = a0[i]*sigf(a0[i]);
        (&z1.x)[i] = a1[i]*sigf(a1[i]);
      }
      *(float4*)&zbuf[0][cb-2048] = z0;
      *(float4*)&zbuf[1][cb-2048] = z1;
    }
    __syncthreads();

    // ---- P2: xdbc partials, 768 threads: (n, 512-K slice) ----
    if (tid < 768){
      const float* wxp = w_x + (size_t)(ks2*512)*192 + n2;
      const int kb = ks2*512;
      float f0 = 0.f, f1 = 0.f;
#pragma unroll 4
      for (int k=0;k<512;k+=4){
        float w0 = wxp[(size_t)(k+0)*192];
        float w1 = wxp[(size_t)(k+1)*192];
        float w2 = wxp[(size_t)(k+2)*192];
        float w3 = wxp[(size_t)(k+3)*192];
        float4 x0 = *(const float4*)&xbuf[0][kb+k];
        float4 x1 = *(const float4*)&xbuf[1][kb+k];
        f0 += x0.x*w0 + x0.y*w1 + x0.z*w2 + x0.w*w3;
        f1 += x1.x*w0 + x1.y*w1 + x1.z*w2 + x1.w*w3;
      }
      *(float2*)&pxd[ks2][n2*2] = make_float2(f0, f1);
    }
    __syncthreads();

    // ---- reduce xdbc (384 threads) ----
    if (tid < 384)
      xdbcF[tid] = pxd[0][tid] + pxd[1][tid] + pxd[2][tid] + pxd[3][tid];
    __syncthreads();

    // ---- bc (128 threads) + dt GEMM (all threads) ----
    if (tid < 128){
      int r = tid >> 6, nl = tid & 63;
      float p = xdbcF[(64+nl)*2 + r] * xdbcF[(128+nl)*2 + r];
#pragma unroll
      for (int sh=1; sh<64; sh<<=1) p += __shfl_xor(p, sh, 64);
      if (nl == 0) bcL[r] = p;
    }
    float d00=0.f, d01=0.f, d10=0.f, d11=0.f;
    {
      const float* wdp = w_dt + c2;
#pragma unroll 8
      for (int o=0;o<64;o++){
        float2 w  = *(const float2*)&wdp[(size_t)o*2048];
        float2 xo = *(const float2*)&xdbcF[o*2];
        d00 += xo.x*w.x; d01 += xo.x*w.y;
        d10 += xo.y*w.x; d11 += xo.y*w.y;
      }
    }
    __syncthreads();   // bcL ready; xbuf (x) still intact

    // ---- y = (softplus(dt)*bc + D) * x * zs, in-place into xbuf ----
    {
      float bc0 = bcL[0], bc1 = bcL[1];
      float2 xr0 = *(const float2*)&xbuf[0][c2];
      float2 xr1 = *(const float2*)&xbuf[1][c2];
      float2 zr0 = *(const float2*)&zbuf[0][c2];
      float2 zr1 = *(const float2*)&zbuf[1][c2];
      float v00 = d00 + bdt2.x, v01 = d01 + bdt2.y;
      float v10 = d10 + bdt2.x, v11 = d11 + bdt2.y;
      float s00 = (v00 > 15.f) ? v00 : __logf(1.f + __expf(v00));
      float s01 = (v01 > 15.f) ? v01 : __logf(1.f + __expf(v01));
      float s10 = (v10 > 15.f) ? v10 : __logf(1.f + __expf(v10));
      float s11 = (v11 > 15.f) ? v11 : __logf(1.f + __expf(v11));
      float y00 = (s00*bc0 + dsk2.x) * xr0.x * zr0.x;
      float y01 = (s01*bc0 + dsk2.y) * xr0.y * zr0.y;
      float y10 = (s10*bc1 + dsk2.x) * xr1.x * zr1.x;
      float y11 = (s11*bc1 + dsk2.y) * xr1.y * zr1.y;
      *(float2*)&xbuf[0][c2] = make_float2(y00, y01);
      *(float2*)&xbuf[1][c2] = make_float2(y10, y11);
    }
    __syncthreads();   // xbuf now holds y

    // ---- P4: pred partials, all threads: (o, 128-K slice) ----
    {
      const float* wpp = W_op + (size_t)kb4*64 + o4;
      float p0 = 0.f, p1 = 0.f;
#pragma unroll 4
      for (int k=0;k<128;k+=4){
        float w0 = wpp[(size_t)(k+0)*64];
        float w1 = wpp[(size_t)(k+1)*64];
        float w2 = wpp[(size_t)(k+2)*64];
        float w3 = wpp[(size_t)(k+3)*64];
        float4 y0 = *(const float4*)&xbuf[0][kb4+k];
        float4 y1 = *(const float4*)&xbuf[1][kb4+k];
        p0 += y0.x*w0 + y0.y*w1 + y0.z*w2 + y0.w*w3;
        p1 += y1.x*w0 + y1.y*w1 + y1.z*w2 + y1.w*w3;
      }
      *(float2*)&ppd[tid>>6][o4*2] = make_float2(p0, p1);
    }
    __syncthreads();

    // ---- reduce pred (128 threads) + dout + next predL ----
    if (tid < 128){
      float v = 0.f;
#pragma unroll
      for (int ks=0; ks<16; ks++) v += ppd[ks][tid];
      predL[tid] = v;
      int o = tid >> 1, r = tid & 1;
      dout[((size_t)(r0+r)*96 + t)*64 + o] = v + bopv;
    }
    __syncthreads();
  }
}

// ---------------- launch ----------------

extern "C" void kernel_launch(void* const* d_in, const int* in_sizes, int n_in,
                              void* d_out, int out_size, void* d_ws, size_t ws_size,
                              hipStream_t stream)
{
  const float* context = (const float*)d_in[0];
  const float* initial = (const float*)d_in[1];
  const float* w_in    = (const float*)d_in[2];
  const float* b_in    = (const float*)d_in[3];
  const float* conv_w  = (const float*)d_in[4];
  const float* conv_b  = (const float*)d_in[5];
  const float* w_x     = (const float*)d_in[6];
  const float* w_dt    = (const float*)d_in[7];
  const float* b_dt    = (const float*)d_in[8];
  // d_in[9] = A_log (unused: L=1, h0=0)
  const float* D_skip  = (const float*)d_in[10];
  const float* w_out   = (const float*)d_in[11];
  const float* b_out   = (const float*)d_in[12];
  const float* w_proj  = (const float*)d_in[13];
  const float* b_proj  = (const float*)d_in[14];

  float* ws = (float*)d_ws;
  float* ctx_xz = ws;                     // 2,097,152
  float* cvec   = ctx_xz + 2097152;       // 4,096
  float* W_op   = cvec + 4096;            // 131,072
  float* b_op   = W_op + 131072;          // 128
  float* dout   = (float*)d_out;

  const float* w_in2 = w_in + (size_t)1024*4096;

  k_wop <<<dim3(513),   256, 0, stream>>>(w_out, w_proj, b_out, b_proj, W_op, b_op);
  k_cvec<<<dim3(16),    256, 0, stream>>>(b_op, w_in2, cvec);
  k_ctx <<<dim3(16,32), 256, 0, stream>>>(context, w_in, b_in, ctx_xz);

  k_steps<<<dim3(256), 1024, 0, stream>>>(ctx_xz, cvec, w_in2, conv_w, conv_b,
                                          w_x, w_dt, b_dt, D_skip, W_op, b_op,
                                          initial, dout);
}

// Round 9
// 2281.464 us; speedup vs baseline: 3.7057x; 1.5927x over previous
//
#include <hip/hip_runtime.h>
#include <math.h>

// B=512, D_MODEL=1024, D_INNER=2048, DT_RANK=64, D_STATE=64, NBC=192,
// C_OUT=64, PRED_LEN=96.
// R9: R8 with the builtin type fixed (__fp16 ext_vector, matching
// __builtin_amdgcn_cvt_pkrtz / __builtin_amdgcn_fdot2 signatures).
// Zero-sync row-stationary: 256 blocks x 1024 threads, 1 block/CU,
// 2 rows/block. f16-packed weights; v_dot2_f32_f16 with fp32 accumulate.

typedef __fp16 half2_t __attribute__((ext_vector_type(2)));
typedef unsigned int uint32;
union HU { uint32 u; half2_t h; };

__device__ __forceinline__ float sigf(float v){
  return __builtin_amdgcn_rcpf(1.f + __expf(-v));
}
__device__ __forceinline__ uint32 pk2(float a, float b){
  HU x; x.h = __builtin_amdgcn_cvt_pkrtz(a, b); return x.u;
}
__device__ __forceinline__ float dot2(uint32 a, uint32 b, float c){
  HU ua, ub; ua.u = a; ub.u = b;
  return __builtin_amdgcn_fdot2(ua.h, ub.h, c, false);
}

// ---------------- setup kernels ----------------

__global__ __launch_bounds__(256) void k_ctx(
    const float* __restrict__ ctxin, const float* __restrict__ w_in,
    const float* __restrict__ b_in, float* __restrict__ ctx_xz){
  int tid = threadIdx.x;
  int j = blockIdx.x*256 + tid;
  int b0 = blockIdx.y*16;
  const float* cp = ctxin + (size_t)b0*1024;
  float acc[16];
#pragma unroll
  for (int r=0;r<16;r++) acc[r]=0.f;
  for (int k=0;k<1024;k+=4){
    float w0 = w_in[(size_t)(k+0)*4096 + j];
    float w1 = w_in[(size_t)(k+1)*4096 + j];
    float w2 = w_in[(size_t)(k+2)*4096 + j];
    float w3 = w_in[(size_t)(k+3)*4096 + j];
#pragma unroll
    for (int r=0;r<16;r++){
      acc[r] += cp[r*1024+k]*w0 + cp[r*1024+k+1]*w1
              + cp[r*1024+k+2]*w2 + cp[r*1024+k+3]*w3;
    }
  }
  float bj = b_in[j];
#pragma unroll
  for (int r=0;r<16;r++) ctx_xz[(size_t)(b0+r)*4096 + j] = acc[r] + bj;
}

// W_op[c][o] = sum_k w_out[c][k]*w_proj[k][o]; b_op = b_out@w_proj + b_proj
__global__ __launch_bounds__(256) void k_wop(
    const float* __restrict__ w_out, const float* __restrict__ w_proj,
    const float* __restrict__ b_out, const float* __restrict__ b_proj,
    float* __restrict__ W_op, float* __restrict__ b_op){
  int g = blockIdx.x, tid = threadIdx.x;
  if (g == 512){
    if (tid < 64){
      float s = b_proj[tid];
      for (int k=0;k<1024;k++) s += b_out[k]*w_proj[k*64+tid];
      b_op[tid] = s;
    }
    return;
  }
  int idx = g*256 + tid;
  int c = idx>>6, o = idx&63;
  float s = 0.f;
  const float* wr = w_out + (size_t)c*1024;
  for (int k=0;k<1024;k++) s += wr[k]*w_proj[k*64+o];
  W_op[idx] = s;
}

__global__ __launch_bounds__(256) void k_cvec(
    const float* __restrict__ b_op, const float* __restrict__ w_in2,
    float* __restrict__ cvec){
  int j = blockIdx.x*256 + threadIdx.x;
  float s = 0.f;
  for (int o=0;o<64;o++) s += b_op[o]*w_in2[(size_t)o*4096 + j];
  cvec[j] = s;
}

// dst[p*inner+i] = pack_f16(src[(2p)*inner+i], src[(2p+1)*inner+i])
__global__ __launch_bounds__(256) void k_pack(
    const float* __restrict__ src, uint32* __restrict__ dst,
    int inner, int total){
  int idx = blockIdx.x*256 + threadIdx.x;
  if (idx >= total) return;
  int p = idx / inner, i = idx - p*inner;
  dst[idx] = pk2(src[(size_t)(2*p)*inner + i], src[(size_t)(2*p+1)*inner + i]);
}

// ---------------- persistent step kernel (no inter-block sync) ----------------

__global__ __launch_bounds__(1024,4) void k_steps(
    const float* __restrict__ ctx_xz, const float* __restrict__ cvec,
    const uint32* __restrict__ h_in2p, const float* __restrict__ conv_w,
    const float* __restrict__ conv_b,  const uint32* __restrict__ wxp,
    const uint32* __restrict__ wdtp,   const float* __restrict__ b_dt,
    const float* __restrict__ D_skip,  const uint32* __restrict__ wopp,
    const float* __restrict__ b_op,    const float* __restrict__ initial,
    float* __restrict__ dout)
{
  const int tid = threadIdx.x;
  const int r0  = blockIdx.x * 2;     // this block's 2 batch rows

  __shared__ uint2  predH2[32];       // pred f16 pairs: [o2] = (row0pair, row1pair)
  __shared__ uint32 xbufH[2][1024];   // x (then y) f16 pairs [r][k2]
  __shared__ float  zbuf[2][2048];    // silu(z), fp32
  __shared__ float  xdbcF[384];       // reduced xdbc [n*2+r], fp32
  __shared__ uint2  xdh2[32];         // xdbc[:, :64] f16 pairs [o2]
  __shared__ float  bcL[2];
  __shared__ float  pxd[4][384];      // xdbc k-slice partials
  __shared__ float  ppd[16][130];     // pred k-slice partials (pad 130)

  // ---- step-invariant per-thread preloads ----
  const int cb = tid*4;               // P1: cols cb..cb+3 of xz (0..4095)
  const bool isx = (cb < 2048);
  float4 cw4, cb4;
  if (isx){
    cw4 = make_float4(conv_w[(cb+0)*4+3], conv_w[(cb+1)*4+3],
                      conv_w[(cb+2)*4+3], conv_w[(cb+3)*4+3]);
    cb4 = *(const float4*)&conv_b[cb];
  }
  const float4 cv4   = *(const float4*)&cvec[cb];
  const float4 ctxr0 = *(const float4*)&ctx_xz[(size_t)(r0+0)*4096 + cb];
  const float4 ctxr1 = *(const float4*)&ctx_xz[(size_t)(r0+1)*4096 + cb];
  const int c2t = tid*2;              // P3: cols c2t, c2t+1 of d_inner
  const float2 bdt2 = *(const float2*)&b_dt[c2t];
  const float2 dsk2 = *(const float2*)&D_skip[c2t];
  const int n2  = tid % 192;          // P2: n x 512-K slice (768 threads)
  const int ks2 = tid / 192;
  const int o4  = tid & 63;           // P4: o x 128-K slice (all threads)
  const int kb2 = (tid >> 6) * 64;    //     k2 base
  const float bopv = b_op[(tid>>1) & 63];

  // init pred = initial, packed to f16 pairs
  if (tid < 128){
    float v = initial[(size_t)(r0 + (tid&1))*64 + (tid>>1)];
    float vp = __shfl_down(v, 2, 64);
    if ((tid & 2) == 0)
      ((uint32*)predH2)[(tid>>2)*2 + (tid&1)] = pk2(v, vp);
  }
  __syncthreads();

  for (int t=0; t<96; t++){
    // ---- P1: xz = ctx (+cvec) + pred @ w_in2 (dot2); x=silu(conv), zs=silu ----
    const float tf = (t > 0) ? 1.f : 0.f;
    float a0[4], a1[4];
#pragma unroll
    for (int i=0;i<4;i++){
      float c = (&cv4.x)[i];
      a0[i] = (&ctxr0.x)[i] + tf*c;
      a1[i] = (&ctxr1.x)[i] + tf*c;
    }
    {
      const uint32* wp = h_in2p + cb;   // [o2][j]
#pragma unroll 8
      for (int o2=0;o2<32;o2++){
        uint4 w  = *(const uint4*)&wp[(size_t)o2*4096];
        uint2 pd = *((const uint2*)predH2 + o2);
        a0[0]=dot2(w.x,pd.x,a0[0]); a0[1]=dot2(w.y,pd.x,a0[1]);
        a0[2]=dot2(w.z,pd.x,a0[2]); a0[3]=dot2(w.w,pd.x,a0[3]);
        a1[0]=dot2(w.x,pd.y,a1[0]); a1[1]=dot2(w.y,pd.y,a1[1]);
        a1[2]=dot2(w.z,pd.y,a1[2]); a1[3]=dot2(w.w,pd.y,a1[3]);
      }
    }
    if (isx){
      float x0[4], x1[4];
#pragma unroll
      for (int i=0;i<4;i++){
        float v0 = a0[i]*(&cw4.x)[i] + (&cb4.x)[i];
        float v1 = a1[i]*(&cw4.x)[i] + (&cb4.x)[i];
        x0[i] = v0*sigf(v0);
        x1[i] = v1*sigf(v1);
      }
      const int p = cb >> 1;
      xbufH[0][p]   = pk2(x0[0], x0[1]);
      xbufH[0][p+1] = pk2(x0[2], x0[3]);
      xbufH[1][p]   = pk2(x1[0], x1[1]);
      xbufH[1][p+1] = pk2(x1[2], x1[3]);
    } else {
      float4 z0, z1;
#pragma unroll
      for (int i=0;i<4;i++){
        (&z0.x)[i] = a0[i]*sigf(a0[i]);
        (&z1.x)[i] = a1[i]*sigf(a1[i]);
      }
      *(float4*)&zbuf[0][cb-2048] = z0;
      *(float4*)&zbuf[1][cb-2048] = z1;
    }
    __syncthreads();

    // ---- P2: xdbc partials (dot2), 768 threads: (n, 256-k2 slice) ----
    if (tid < 768){
      const uint32* wxpp = wxp + (size_t)(ks2*256)*192 + n2;
      const int kb = ks2*256;
      float f0 = 0.f, f1 = 0.f;
#pragma unroll 4
      for (int k2=0;k2<256;k2++){
        uint32 w  = wxpp[(size_t)k2*192];
        uint32 x0 = xbufH[0][kb+k2];
        uint32 x1 = xbufH[1][kb+k2];
        f0 = dot2(w, x0, f0);
        f1 = dot2(w, x1, f1);
      }
      *(float2*)&pxd[ks2][n2*2] = make_float2(f0, f1);
    }
    __syncthreads();

    // ---- reduce xdbc (384 threads) ----
    if (tid < 384)
      xdbcF[tid] = pxd[0][tid] + pxd[1][tid] + pxd[2][tid] + pxd[3][tid];
    __syncthreads();

    // ---- bc (128 threads) + pack xdbc_dt pairs (32 threads) ----
    if (tid < 128){
      int r = tid >> 6, nl = tid & 63;
      float p = xdbcF[(64+nl)*2 + r] * xdbcF[(128+nl)*2 + r];
#pragma unroll
      for (int sh=1; sh<64; sh<<=1) p += __shfl_xor(p, sh, 64);
      if (nl == 0) bcL[r] = p;
    } else if (tid < 160){
      int o2 = tid - 128;
      float v00 = xdbcF[(2*o2  )*2 + 0], v01 = xdbcF[(2*o2  )*2 + 1];
      float v10 = xdbcF[(2*o2+1)*2 + 0], v11 = xdbcF[(2*o2+1)*2 + 1];
      ((uint32*)xdh2)[o2*2+0] = pk2(v00, v10);
      ((uint32*)xdh2)[o2*2+1] = pk2(v01, v11);
    }
    __syncthreads();

    // ---- dt GEMM (dot2, K=64) + y (in-place y -> xbufH) ----
    float d00=0.f, d01=0.f, d10=0.f, d11=0.f;
    {
      const uint32* wd = wdtp + c2t;   // [o2][c]
#pragma unroll 8
      for (int o2=0;o2<32;o2++){
        uint2 w  = *(const uint2*)&wd[(size_t)o2*2048];
        uint2 xd = *((const uint2*)xdh2 + o2);
        d00 = dot2(w.x, xd.x, d00);
        d01 = dot2(w.y, xd.x, d01);
        d10 = dot2(w.x, xd.y, d10);
        d11 = dot2(w.y, xd.y, d11);
      }
    }
    {
      float bc0 = bcL[0], bc1 = bcL[1];
      HU xh0, xh1; xh0.u = xbufH[0][tid]; xh1.u = xbufH[1][tid];
      float2 zr0 = *(const float2*)&zbuf[0][c2t];
      float2 zr1 = *(const float2*)&zbuf[1][c2t];
      float v00 = d00 + bdt2.x, v01 = d01 + bdt2.y;
      float v10 = d10 + bdt2.x, v11 = d11 + bdt2.y;
      float s00 = (v00 > 15.f) ? v00 : __logf(1.f + __expf(v00));
      float s01 = (v01 > 15.f) ? v01 : __logf(1.f + __expf(v01));
      float s10 = (v10 > 15.f) ? v10 : __logf(1.f + __expf(v10));
      float s11 = (v11 > 15.f) ? v11 : __logf(1.f + __expf(v11));
      float y00 = (s00*bc0 + dsk2.x) * (float)xh0.h.x * zr0.x;
      float y01 = (s01*bc0 + dsk2.y) * (float)xh0.h.y * zr0.y;
      float y10 = (s10*bc1 + dsk2.x) * (float)xh1.h.x * zr1.x;
      float y11 = (s11*bc1 + dsk2.y) * (float)xh1.h.y * zr1.y;
      // same-thread read-then-write of xbufH[.][tid]: no cross-thread hazard
      xbufH[0][tid] = pk2(y00, y01);
      xbufH[1][tid] = pk2(y10, y11);
    }
    __syncthreads();

    // ---- P4: pred partials (dot2), all threads: (o, 64-k2 slice) ----
    {
      const uint32* wo = wopp + (size_t)kb2*64 + o4;
      float p0 = 0.f, p1 = 0.f;
#pragma unroll 4
      for (int k2=0;k2<64;k2++){
        uint32 w  = wo[(size_t)k2*64];
        uint32 y0 = xbufH[0][kb2+k2];
        uint32 y1 = xbufH[1][kb2+k2];
        p0 = dot2(w, y0, p0);
        p1 = dot2(w, y1, p1);
      }
      *(float2*)&ppd[tid>>6][o4*2] = make_float2(p0, p1);
    }
    __syncthreads();

    // ---- reduce pred (128 threads) + dout + pack next predH2 ----
    if (tid < 128){
      float v = 0.f;
#pragma unroll
      for (int ks=0; ks<16; ks++) v += ppd[ks][tid];
      int o = tid >> 1, r = tid & 1;
      dout[((size_t)(r0+r)*96 + t)*64 + o] = v + bopv;
      float vp = __shfl_down(v, 2, 64);
      if ((tid & 2) == 0)
        ((uint32*)predH2)[(tid>>2)*2 + (tid&1)] = pk2(v, vp);
    }
    __syncthreads();
  }
}

// ---------------- launch ----------------

extern "C" void kernel_launch(void* const* d_in, const int* in_sizes, int n_in,
                              void* d_out, int out_size, void* d_ws, size_t ws_size,
                              hipStream_t stream)
{
  const float* context = (const float*)d_in[0];
  const float* initial = (const float*)d_in[1];
  const float* w_in    = (const float*)d_in[2];
  const float* b_in    = (const float*)d_in[3];
  const float* conv_w  = (const float*)d_in[4];
  const float* conv_b  = (const float*)d_in[5];
  const float* w_x     = (const float*)d_in[6];
  const float* w_dt    = (const float*)d_in[7];
  const float* b_dt    = (const float*)d_in[8];
  // d_in[9] = A_log (unused: L=1, h0=0)
  const float* D_skip  = (const float*)d_in[10];
  const float* w_out   = (const float*)d_in[11];
  const float* b_out   = (const float*)d_in[12];
  const float* w_proj  = (const float*)d_in[13];
  const float* b_proj  = (const float*)d_in[14];

  float* ws = (float*)d_ws;
  float*  ctx_xz = ws;                       // 2,097,152 f
  float*  cvec   = ctx_xz + 2097152;         // 4,096 f
  float*  W_op   = cvec + 4096;              // 131,072 f
  float*  b_op   = W_op + 131072;            // 128 f
  uint32* h_in2p = (uint32*)(b_op + 128);    // 131,072 u  [32][4096]
  uint32* wxp    = h_in2p + 131072;          // 196,608 u  [1024][192]
  uint32* wdtp   = wxp + 196608;             // 65,536 u   [32][2048]
  uint32* wopp   = wdtp + 65536;             // 65,536 u   [1024][64]
  float*  dout   = (float*)d_out;

  const float* w_in2 = w_in + (size_t)1024*4096;

  k_wop <<<dim3(513),   256, 0, stream>>>(w_out, w_proj, b_out, b_proj, W_op, b_op);
  k_cvec<<<dim3(16),    256, 0, stream>>>(b_op, w_in2, cvec);
  k_ctx <<<dim3(16,32), 256, 0, stream>>>(context, w_in, b_in, ctx_xz);
  k_pack<<<dim3(512),   256, 0, stream>>>(w_in2, h_in2p, 4096, 131072);
  k_pack<<<dim3(768),   256, 0, stream>>>(w_x,   wxp,    192,  196608);
  k_pack<<<dim3(256),   256, 0, stream>>>(w_dt,  wdtp,   2048, 65536);
  k_pack<<<dim3(256),   256, 0, stream>>>(W_op,  wopp,   64,   65536);

  k_steps<<<dim3(256), 1024, 0, stream>>>(ctx_xz, cvec, h_in2p, conv_w, conv_b,
                                          wxp, wdtp, b_dt, D_skip, wopp, b_op,
                                          initial, dout);
}